// Round 1
// baseline (369.536 us; speedup 1.0000x reference)
//
#include <hip/hip_runtime.h>
#include <hip/hip_bf16.h>

// RGCN layer: out = relu(h@W0 + segment_sum(norm * h[src] @ W[rel], dst))
// Restructured: per-node per-relation aggregation in IN space, then ONE
// [N, 768] @ [768, 128] bf16 MFMA GEMM (5 stacked W_r + W0), relu fused.
// This avoids 76.8M fp32 atomics (atomic-throughput floor ~250us) and the
// 256MB all_h intermediate.

#define NN   100000
#define NE   600000
#define FEAT 128
#define RNUM 5
#define KTOT 768   // 5*128 (relations) + 128 (W0/identity part)

typedef __attribute__((ext_vector_type(8))) short short8;
typedef __attribute__((ext_vector_type(4))) float float4v;

static __device__ __forceinline__ unsigned short f2bf(float x) {
  union { float f; unsigned u; } v; v.f = x;
  unsigned r = v.u + 0x7FFFu + ((v.u >> 16) & 1u);  // RNE
  return (unsigned short)(r >> 16);
}

// ---- bucket edges by dst ----------------------------------------------------
__global__ void k_hist(const int* __restrict__ dst, int* __restrict__ deg) {
  int e = blockIdx.x * 256 + threadIdx.x;
  if (e < NE) atomicAdd(&deg[dst[e]], 1);
}

// Unordered segment allocation: segments need not be sorted, only contiguous
// per node -> no prefix scan needed, one atomic per node.
__global__ void k_alloc(const int* __restrict__ deg, int* __restrict__ offs,
                        int* __restrict__ cursor, int* __restrict__ total) {
  int n = blockIdx.x * 256 + threadIdx.x;
  if (n < NN) {
    int d = deg[n];
    int s = atomicAdd(total, d);
    offs[n] = s;
    cursor[n] = s;
  }
}

__global__ void k_scatter(const int* __restrict__ src, const int* __restrict__ dst,
                          const int* __restrict__ eid, const float* __restrict__ norm,
                          int* __restrict__ cursor, int* __restrict__ s_packed,
                          float* __restrict__ s_norm) {
  int e = blockIdx.x * 256 + threadIdx.x;
  if (e < NE) {
    int p = atomicAdd(&cursor[dst[e]], 1);
    s_packed[p] = src[e] | (eid[e] << 20);   // src < 2^17, rel < 8
    s_norm[p] = norm[e];
  }
}

// ---- build stacked/transposed bf16 weights Bt[o][k], k = rel*128+i or 640+i (W0)
__global__ void k_wt(const float* __restrict__ weight, const float* __restrict__ W0,
                     unsigned short* __restrict__ Bt) {
  int t = blockIdx.x * 256 + threadIdx.x;
  if (t < FEAT * KTOT) {
    int o = t / KTOT;
    int k = t - o * KTOT;
    float v = (k < 640) ? weight[(k >> 7) * 16384 + (k & 127) * 128 + o]
                        : W0[(k - 640) * 128 + o];
    Bt[t] = f2bf(v);
  }
}

// ---- per-node aggregation: one wave per node, lane handles feats (lane, lane+64)
__global__ void k_agg(const float* __restrict__ h, const int* __restrict__ offs,
                      const int* __restrict__ deg, const int* __restrict__ s_packed,
                      const float* __restrict__ s_norm, unsigned short* __restrict__ A) {
  int wave = (blockIdx.x * 256 + threadIdx.x) >> 6;
  int lane = threadIdx.x & 63;
  if (wave >= NN) return;
  int n = wave;
  int start = offs[n], len = deg[n];
  float acc[RNUM][2] = {};
  for (int j = 0; j < len; ++j) {
    int p = s_packed[start + j];
    float nm = s_norm[start + j];
    int s = p & 0xFFFFF;
    int r = p >> 20;
    float h0 = h[s * 128 + lane];          // coalesced 256B gather (h LLC-resident)
    float h1 = h[s * 128 + 64 + lane];
#pragma unroll
    for (int rr = 0; rr < RNUM; ++rr) {
      if (r == rr) { acc[rr][0] += nm * h0; acc[rr][1] += nm * h1; }
    }
  }
  unsigned short* Arow = A + (size_t)n * KTOT;
#pragma unroll
  for (int rr = 0; rr < RNUM; ++rr) {
    Arow[rr * 128 + lane]      = f2bf(acc[rr][0]);
    Arow[rr * 128 + 64 + lane] = f2bf(acc[rr][1]);
  }
  Arow[640 + lane]      = f2bf(h[n * 128 + lane]);
  Arow[640 + 64 + lane] = f2bf(h[n * 128 + 64 + lane]);
}

// ---- GEMM: [NN x 768] @ [768 x 128], bf16 MFMA 16x16x32, relu fused ---------
// Block = 256 (4 waves), each wave = 16-row strip x 128 cols (8 n-tiles).
// B chunk staged in LDS in FRAG-LINEAR order -> ds_read_b128 at lane*16B,
// conflict-free. A rows read from global exactly once (16B/lane loads).
__global__ __launch_bounds__(256, 4) void k_gemm(
    const unsigned short* __restrict__ A, const unsigned short* __restrict__ Bt,
    float* __restrict__ out) {
  __shared__ __align__(16) unsigned short Bl[4 * 8 * 64 * 8];  // 32 KiB
  int tid = threadIdx.x;
  int wv = tid >> 6, lane = tid & 63;
  int m = lane & 15, q = lane >> 4;
  int row0 = blockIdx.x * 64 + wv * 16;
  float4v acc[8];
#pragma unroll
  for (int i = 0; i < 8; ++i) acc[i] = (float4v){0.f, 0.f, 0.f, 0.f};

  int arow = row0 + m;
  if (arow >= NN) arow = NN - 1;            // clamp; store is guarded
  const unsigned short* Ap = A + (size_t)arow * KTOT + q * 8;

  for (int kc = 0; kc < 6; ++kc) {
    // stage B chunk kc (128 k-values) into frag-linear LDS
    for (int i = tid; i < 2048; i += 256) {
      int ks = i >> 9, n0 = (i >> 6) & 7, ln = i & 63;
      int bn = n0 * 16 + (ln & 15);
      int bk = kc * 128 + ks * 32 + ((ln >> 4) << 3);
      *(short8*)&Bl[i * 8] = *(const short8*)&Bt[bn * KTOT + bk];
    }
    __syncthreads();
#pragma unroll
    for (int ks = 0; ks < 4; ++ks) {
      short8 af = *(const short8*)(Ap + kc * 128 + ks * 32);
#pragma unroll
      for (int n0 = 0; n0 < 8; ++n0) {
        short8 bf = *(const short8*)&Bl[((ks * 8 + n0) * 64 + lane) * 8];
        acc[n0] = __builtin_amdgcn_mfma_f32_16x16x32_bf16(af, bf, acc[n0], 0, 0, 0);
      }
    }
    __syncthreads();
  }
  // epilogue: C/D layout col=lane&15, row=q*4+reg  [m89-verified]
#pragma unroll
  for (int n0 = 0; n0 < 8; ++n0) {
#pragma unroll
    for (int r = 0; r < 4; ++r) {
      int row = row0 + q * 4 + r;
      if (row < NN) {
        float v = acc[n0][r];
        out[(size_t)row * FEAT + n0 * 16 + m] = v > 0.f ? v : 0.f;
      }
    }
  }
}

// ---- slow-but-correct fallback if ws_size is too small ----------------------
__global__ void k_slow_mm(const float* __restrict__ h, const float* __restrict__ W0,
                          float* __restrict__ out) {
  __shared__ float hn[128];
  int n = blockIdx.x, t = threadIdx.x;
  hn[t] = h[(size_t)n * 128 + t];
  __syncthreads();
  float a = 0.f;
  for (int i = 0; i < 128; ++i) a += hn[i] * W0[i * 128 + t];
  out[(size_t)n * 128 + t] = a;
}
__global__ void k_slow_edge(const float* __restrict__ h, const float* __restrict__ weight,
                            const float* __restrict__ norm, const int* __restrict__ src,
                            const int* __restrict__ dst, const int* __restrict__ eid,
                            float* __restrict__ out) {
  __shared__ float hs[128];
  int e = blockIdx.x, t = threadIdx.x;
  hs[t] = h[(size_t)src[e] * 128 + t];
  __syncthreads();
  const float* W = weight + (size_t)eid[e] * 16384;
  float a = 0.f;
  for (int i = 0; i < 128; ++i) a += hs[i] * W[i * 128 + t];
  atomicAdd(&out[(size_t)dst[e] * 128 + t], a * norm[e]);
}
__global__ void k_slow_relu(float* out) {
  int i = blockIdx.x * 256 + threadIdx.x;
  if (i < NN * FEAT) out[i] = fmaxf(out[i], 0.f);
}

extern "C" void kernel_launch(void* const* d_in, const int* in_sizes, int n_in,
                              void* d_out, int out_size, void* d_ws, size_t ws_size,
                              hipStream_t stream) {
  const float* h      = (const float*)d_in[0];
  const float* weight = (const float*)d_in[1];
  const float* W0     = (const float*)d_in[2];
  const float* norm   = (const float*)d_in[3];
  const int*   src    = (const int*)d_in[4];
  const int*   dst    = (const int*)d_in[5];
  const int*   eid    = (const int*)d_in[6];
  float* out = (float*)d_out;

  char* ws = (char*)d_ws;
  size_t off = 0;
  auto wsalloc = [&](size_t bytes) -> char* {
    char* p = ws + off;
    off += (bytes + 255) & ~(size_t)255;
    return p;
  };
  unsigned short* A   = (unsigned short*)wsalloc((size_t)NN * KTOT * 2);  // 153.6 MB
  unsigned short* Bt  = (unsigned short*)wsalloc((size_t)FEAT * KTOT * 2);
  int*   deg      = (int*)wsalloc((size_t)NN * 4);
  int*   offs     = (int*)wsalloc((size_t)NN * 4);
  int*   cursor   = (int*)wsalloc((size_t)NN * 4);
  int*   total    = (int*)wsalloc(256);
  int*   s_packed = (int*)wsalloc((size_t)NE * 4);
  float* s_norm   = (float*)wsalloc((size_t)NE * 4);

  if (ws_size >= off) {
    hipMemsetAsync(deg, 0, (size_t)NN * 4, stream);
    hipMemsetAsync(total, 0, 4, stream);
    k_hist   <<<(NE + 255) / 256, 256, 0, stream>>>(dst, deg);
    k_alloc  <<<(NN + 255) / 256, 256, 0, stream>>>(deg, offs, cursor, total);
    k_scatter<<<(NE + 255) / 256, 256, 0, stream>>>(src, dst, eid, norm, cursor,
                                                    s_packed, s_norm);
    k_wt     <<<(FEAT * KTOT + 255) / 256, 256, 0, stream>>>(weight, W0, Bt);
    k_agg    <<<(NN + 3) / 4, 256, 0, stream>>>(h, offs, deg, s_packed, s_norm, A);
    k_gemm   <<<(NN + 63) / 64, 256, 0, stream>>>(A, Bt, out);
  } else {
    // workspace too small for the fast path: correct fallback (learn ws_size)
    k_slow_mm  <<<NN, 128, 0, stream>>>(h, W0, out);
    k_slow_edge<<<NE, 128, 0, stream>>>(h, weight, norm, src, dst, eid, out);
    k_slow_relu<<<(NN * FEAT + 255) / 256, 256, 0, stream>>>(out);
  }
}

// Round 2
// 352.638 us; speedup vs baseline: 1.0479x; 1.0479x over previous
//
#include <hip/hip_runtime.h>
#include <hip/hip_bf16.h>

// RGCN layer: out = relu(h@W0 + segment_sum(norm * h[src] @ W[rel], dst))
// Strategy: per-(node,relation) aggregation in IN space (640-wide A),
// then ONE [N, 768] @ [768, 128] bf16 MFMA GEMM where the last 128-wide
// k-chunk of A is read directly from hb (bf16 h) instead of materialized.
// R2: gather from bf16 hb (halves gather bytes, working set ~fits L2).

#define NN   100000
#define NE   600000
#define FEAT 128
#define RNUM 5
#define KTOT 768   // GEMM K: 5*128 (relations) + 128 (identity/W0 part)
#define KA   640   // materialized A width (relations only)

typedef __attribute__((ext_vector_type(8))) short short8;
typedef __attribute__((ext_vector_type(4))) float float4v;

static __device__ __forceinline__ unsigned short f2bf(float x) {
  union { float f; unsigned u; } v; v.f = x;
  unsigned r = v.u + 0x7FFFu + ((v.u >> 16) & 1u);  // RNE
  return (unsigned short)(r >> 16);
}

// ---- bucket edges by dst ----------------------------------------------------
__global__ void k_hist(const int* __restrict__ dst, int* __restrict__ deg) {
  int e = blockIdx.x * 256 + threadIdx.x;
  if (e < NE) atomicAdd(&deg[dst[e]], 1);
}

// Unordered segment allocation: segments need not be sorted, only contiguous
// per node -> no prefix scan, one atomic per node.
__global__ void k_alloc(const int* __restrict__ deg, int* __restrict__ offs,
                        int* __restrict__ cursor, int* __restrict__ total) {
  int n = blockIdx.x * 256 + threadIdx.x;
  if (n < NN) {
    int d = deg[n];
    int s = atomicAdd(total, d);
    offs[n] = s;
    cursor[n] = s;
  }
}

__global__ void k_scatter(const int* __restrict__ src, const int* __restrict__ dst,
                          const int* __restrict__ eid, const float* __restrict__ norm,
                          int* __restrict__ cursor, int* __restrict__ s_packed,
                          float* __restrict__ s_norm) {
  int e = blockIdx.x * 256 + threadIdx.x;
  if (e < NE) {
    int p = atomicAdd(&cursor[dst[e]], 1);
    s_packed[p] = src[e] | (eid[e] << 20);   // src < 2^17, rel < 8
    s_norm[p] = norm[e];
  }
}

// ---- fused prep: h -> bf16 hb, plus stacked/transposed bf16 weights Bt[o][k]
// k = rel*128 + i for relations, 640+i for W0.
__global__ void k_prep(const float* __restrict__ h, const float* __restrict__ weight,
                       const float* __restrict__ W0, unsigned short* __restrict__ hb,
                       unsigned short* __restrict__ Bt) {
  int t = blockIdx.x * 256 + threadIdx.x;
  if (t < NN * 32) {                       // 4 elements per thread
    float4v v = *(const float4v*)(h + (size_t)t * 4);
    unsigned long long p = (unsigned long long)f2bf(v[0])
                         | ((unsigned long long)f2bf(v[1]) << 16)
                         | ((unsigned long long)f2bf(v[2]) << 32)
                         | ((unsigned long long)f2bf(v[3]) << 48);
    *(unsigned long long*)(hb + (size_t)t * 4) = p;
  } else {
    int u = t - NN * 32;
    if (u < FEAT * KTOT) {
      int o = u / KTOT;
      int k = u - o * KTOT;
      float v = (k < 640) ? weight[(k >> 7) * 16384 + (k & 127) * 128 + o]
                          : W0[(k - 640) * 128 + o];
      Bt[u] = f2bf(v);
    }
  }
}

// ---- per-node aggregation: one wave per node, lane handles feats (2L, 2L+1)
__global__ void k_agg(const unsigned short* __restrict__ hb, const int* __restrict__ offs,
                      const int* __restrict__ deg, const int* __restrict__ s_packed,
                      const float* __restrict__ s_norm, unsigned short* __restrict__ A) {
  int wave = (blockIdx.x * 256 + threadIdx.x) >> 6;
  int lane = threadIdx.x & 63;
  if (wave >= NN) return;
  int start = offs[wave], len = deg[wave];
  float acc[RNUM][2] = {};
  const unsigned* hbp = (const unsigned*)hb;
  for (int j = 0; j < len; ++j) {
    int p = s_packed[start + j];
    float nm = s_norm[start + j];
    int s = p & 0xFFFFF;
    int r = p >> 20;
    unsigned v = hbp[s * 64 + lane];       // coalesced 256B bf16 gather
    union { unsigned u; float f; } lo, hi;
    lo.u = v << 16;
    hi.u = v & 0xFFFF0000u;
#pragma unroll
    for (int rr = 0; rr < RNUM; ++rr) {
      if (r == rr) { acc[rr][0] += nm * lo.f; acc[rr][1] += nm * hi.f; }
    }
  }
  unsigned* Arow = (unsigned*)(A + (size_t)wave * KA);
#pragma unroll
  for (int rr = 0; rr < RNUM; ++rr) {
    Arow[rr * 64 + lane] = (unsigned)f2bf(acc[rr][0])
                         | ((unsigned)f2bf(acc[rr][1]) << 16);
  }
}

// ---- GEMM: [NN x 768] @ [768 x 128], bf16 MFMA 16x16x32, relu fused ---------
// Block = 256 (4 waves), each wave = 16-row strip x 128 cols (8 n-tiles).
// k-chunks 0..4 read from A (stride 640); chunk 5 reads hb directly.
// B chunk staged in LDS in FRAG-LINEAR order -> ds_read_b128 at lane*16B,
// conflict-free.
__global__ __launch_bounds__(256, 4) void k_gemm(
    const unsigned short* __restrict__ A, const unsigned short* __restrict__ hb,
    const unsigned short* __restrict__ Bt, float* __restrict__ out) {
  __shared__ __align__(16) unsigned short Bl[4 * 8 * 64 * 8];  // 32 KiB
  int tid = threadIdx.x;
  int wv = tid >> 6, lane = tid & 63;
  int m = lane & 15, q = lane >> 4;
  int row0 = blockIdx.x * 64 + wv * 16;
  float4v acc[8];
#pragma unroll
  for (int i = 0; i < 8; ++i) acc[i] = (float4v){0.f, 0.f, 0.f, 0.f};

  int arow = row0 + m;
  if (arow >= NN) arow = NN - 1;            // clamp; store is guarded
  const unsigned short* Ap = A + (size_t)arow * KA + q * 8;
  const unsigned short* Hp = hb + (size_t)arow * FEAT + q * 8;

  for (int kc = 0; kc < 6; ++kc) {
    // stage B chunk kc (128 k-values x 128 n) into frag-linear LDS
    for (int i = tid; i < 2048; i += 256) {
      int ks = i >> 9, n0 = (i >> 6) & 7, ln = i & 63;
      int bn = n0 * 16 + (ln & 15);
      int bk = kc * 128 + ks * 32 + ((ln >> 4) << 3);
      *(short8*)&Bl[i * 8] = *(const short8*)&Bt[bn * KTOT + bk];
    }
    __syncthreads();
    const unsigned short* abase = (kc < 5) ? (Ap + kc * 128) : Hp;
#pragma unroll
    for (int ks = 0; ks < 4; ++ks) {
      short8 af = *(const short8*)(abase + ks * 32);
#pragma unroll
      for (int n0 = 0; n0 < 8; ++n0) {
        short8 bf = *(const short8*)&Bl[((ks * 8 + n0) * 64 + lane) * 8];
        acc[n0] = __builtin_amdgcn_mfma_f32_16x16x32_bf16(af, bf, acc[n0], 0, 0, 0);
      }
    }
    __syncthreads();
  }
  // epilogue: C/D layout col=lane&15, row=q*4+reg  [m89-verified]
#pragma unroll
  for (int n0 = 0; n0 < 8; ++n0) {
#pragma unroll
    for (int r = 0; r < 4; ++r) {
      int row = row0 + q * 4 + r;
      if (row < NN) {
        float v = acc[n0][r];
        out[(size_t)row * FEAT + n0 * 16 + m] = v > 0.f ? v : 0.f;
      }
    }
  }
}

// ---- slow-but-correct fallback if ws_size is too small ----------------------
__global__ void k_slow_mm(const float* __restrict__ h, const float* __restrict__ W0,
                          float* __restrict__ out) {
  __shared__ float hn[128];
  int n = blockIdx.x, t = threadIdx.x;
  hn[t] = h[(size_t)n * 128 + t];
  __syncthreads();
  float a = 0.f;
  for (int i = 0; i < 128; ++i) a += hn[i] * W0[i * 128 + t];
  out[(size_t)n * 128 + t] = a;
}
__global__ void k_slow_edge(const float* __restrict__ h, const float* __restrict__ weight,
                            const float* __restrict__ norm, const int* __restrict__ src,
                            const int* __restrict__ dst, const int* __restrict__ eid,
                            float* __restrict__ out) {
  __shared__ float hs[128];
  int e = blockIdx.x, t = threadIdx.x;
  hs[t] = h[(size_t)src[e] * 128 + t];
  __syncthreads();
  const float* W = weight + (size_t)eid[e] * 16384;
  float a = 0.f;
  for (int i = 0; i < 128; ++i) a += hs[i] * W[i * 128 + t];
  atomicAdd(&out[(size_t)dst[e] * 128 + t], a * norm[e]);
}
__global__ void k_slow_relu(float* out) {
  int i = blockIdx.x * 256 + threadIdx.x;
  if (i < NN * FEAT) out[i] = fmaxf(out[i], 0.f);
}

extern "C" void kernel_launch(void* const* d_in, const int* in_sizes, int n_in,
                              void* d_out, int out_size, void* d_ws, size_t ws_size,
                              hipStream_t stream) {
  const float* h      = (const float*)d_in[0];
  const float* weight = (const float*)d_in[1];
  const float* W0     = (const float*)d_in[2];
  const float* norm   = (const float*)d_in[3];
  const int*   src    = (const int*)d_in[4];
  const int*   dst    = (const int*)d_in[5];
  const int*   eid    = (const int*)d_in[6];
  float* out = (float*)d_out;

  char* ws = (char*)d_ws;
  size_t off = 0;
  auto wsalloc = [&](size_t bytes) -> char* {
    char* p = ws + off;
    off += (bytes + 255) & ~(size_t)255;
    return p;
  };
  unsigned short* A   = (unsigned short*)wsalloc((size_t)NN * KA * 2);    // 128 MB
  unsigned short* hb  = (unsigned short*)wsalloc((size_t)NN * FEAT * 2);  // 25.6 MB
  unsigned short* Bt  = (unsigned short*)wsalloc((size_t)FEAT * KTOT * 2);
  int*   deg      = (int*)wsalloc((size_t)NN * 4);
  int*   offs     = (int*)wsalloc((size_t)NN * 4);
  int*   cursor   = (int*)wsalloc((size_t)NN * 4);
  int*   total    = (int*)wsalloc(256);
  int*   s_packed = (int*)wsalloc((size_t)NE * 4);
  float* s_norm   = (float*)wsalloc((size_t)NE * 4);

  if (ws_size >= off) {
    hipMemsetAsync(deg, 0, (size_t)NN * 4, stream);
    hipMemsetAsync(total, 0, 4, stream);
    k_hist   <<<(NE + 255) / 256, 256, 0, stream>>>(dst, deg);
    k_alloc  <<<(NN + 255) / 256, 256, 0, stream>>>(deg, offs, cursor, total);
    k_scatter<<<(NE + 255) / 256, 256, 0, stream>>>(src, dst, eid, norm, cursor,
                                                    s_packed, s_norm);
    k_prep   <<<(NN * 32 + FEAT * KTOT + 255) / 256, 256, 0, stream>>>(h, weight, W0,
                                                                       hb, Bt);
    k_agg    <<<(NN + 3) / 4, 256, 0, stream>>>(hb, offs, deg, s_packed, s_norm, A);
    k_gemm   <<<(NN + 63) / 64, 256, 0, stream>>>(A, hb, Bt, out);
  } else {
    // workspace too small for the fast path: correct fallback
    k_slow_mm  <<<NN, 128, 0, stream>>>(h, W0, out);
    k_slow_edge<<<NE, 128, 0, stream>>>(h, weight, norm, src, dst, eid, out);
    k_slow_relu<<<(NN * FEAT + 255) / 256, 256, 0, stream>>>(out);
  }
}

// Round 3
// 313.152 us; speedup vs baseline: 1.1801x; 1.1261x over previous
//
#include <hip/hip_runtime.h>
#include <hip/hip_bf16.h>

// RGCN layer: out = relu(h@W0 + segment_sum(norm * h[src] @ W[rel], dst))
// Strategy: per-(node,relation) aggregation in IN space (640-wide bf16 A),
// then ONE [N, 768] @ [768, 128] bf16 MFMA GEMM where the last 128-wide
// k-chunk of A is read directly from hb (bf16 h).
// R3: 4-deep pipelined gather in k_agg (was serial dep-chain, latency-bound),
//     int2 edge records (1 store/load per edge), hist+prep merged.

#define NN   100000
#define NE   600000
#define FEAT 128
#define RNUM 5
#define KTOT 768   // GEMM K: 5*128 (relations) + 128 (identity/W0 part)
#define KA   640   // materialized A width (relations only)

#define HIST_B 2344            // ceil(NE/256)
#define PREP_T (NN * 32 + FEAT * KTOT)
#define PREP_B ((PREP_T + 255) / 256)

typedef __attribute__((ext_vector_type(8))) short short8;
typedef __attribute__((ext_vector_type(4))) float float4v;

static __device__ __forceinline__ unsigned short f2bf(float x) {
  union { float f; unsigned u; } v; v.f = x;
  unsigned r = v.u + 0x7FFFu + ((v.u >> 16) & 1u);  // RNE
  return (unsigned short)(r >> 16);
}

// ---- merged: dst histogram + (h -> bf16 hb, stacked/transposed bf16 Bt) -----
__global__ void k_setup(const int* __restrict__ dst, const float* __restrict__ h,
                        const float* __restrict__ weight, const float* __restrict__ W0,
                        int* __restrict__ deg, unsigned short* __restrict__ hb,
                        unsigned short* __restrict__ Bt, int* __restrict__ total) {
  int bid = blockIdx.x;
  if (bid == 0 && threadIdx.x == 0) *total = 0;
  if (bid < HIST_B) {
    int e = bid * 256 + threadIdx.x;
    if (e < NE) atomicAdd(&deg[dst[e]], 1);
  } else {
    int t = (bid - HIST_B) * 256 + threadIdx.x;
    if (t < NN * 32) {                     // 4 h-elements per thread
      float4v v = *(const float4v*)(h + (size_t)t * 4);
      unsigned long long p = (unsigned long long)f2bf(v[0])
                           | ((unsigned long long)f2bf(v[1]) << 16)
                           | ((unsigned long long)f2bf(v[2]) << 32)
                           | ((unsigned long long)f2bf(v[3]) << 48);
      *(unsigned long long*)(hb + (size_t)t * 4) = p;
    } else {
      int u = t - NN * 32;
      if (u < FEAT * KTOT) {
        int o = u / KTOT;
        int k = u - o * KTOT;
        float v = (k < 640) ? weight[(k >> 7) * 16384 + (k & 127) * 128 + o]
                            : W0[(k - 640) * 128 + o];
        Bt[u] = f2bf(v);
      }
    }
  }
}

// Unordered segment allocation: segments need not be sorted, only contiguous
// per node -> no prefix scan, one atomic per node.
__global__ void k_alloc(const int* __restrict__ deg, int* __restrict__ offs,
                        int* __restrict__ cursor, int* __restrict__ total) {
  int n = blockIdx.x * 256 + threadIdx.x;
  if (n < NN) {
    int d = deg[n];
    int s = atomicAdd(total, d);
    offs[n] = s;
    cursor[n] = s;
  }
}

__global__ void k_scatter(const int* __restrict__ src, const int* __restrict__ dst,
                          const int* __restrict__ eid, const float* __restrict__ norm,
                          int* __restrict__ cursor, int2* __restrict__ s_edge) {
  int e = blockIdx.x * 256 + threadIdx.x;
  if (e < NE) {
    int p = atomicAdd(&cursor[dst[e]], 1);
    union { float f; int i; } nb; nb.f = norm[e];
    s_edge[p] = make_int2(src[e] | (eid[e] << 20), nb.i);  // one 8B record
  }
}

// ---- per-node aggregation: one wave per node, lane covers feats (2L, 2L+1) --
// 4-deep manual pipeline: 4 independent edge-record loads, then 4 independent
// 256B gathers in flight, then the fmacs.
__global__ void k_agg(const unsigned short* __restrict__ hb, const int* __restrict__ offs,
                      const int* __restrict__ deg, const int2* __restrict__ s_edge,
                      unsigned short* __restrict__ A) {
  int wave = (blockIdx.x * 256 + threadIdx.x) >> 6;
  int lane = threadIdx.x & 63;
  if (wave >= NN) return;
  int start = offs[wave], len = deg[wave];
  float acc[RNUM][2] = {};
  const unsigned* hbp = (const unsigned*)hb;
  const int2* ep = s_edge + start;

  int j = 0;
  for (; j + 4 <= len; j += 4) {
    int2 e0 = ep[j], e1 = ep[j + 1], e2 = ep[j + 2], e3 = ep[j + 3];
    unsigned v0 = hbp[(e0.x & 0xFFFFF) * 64 + lane];
    unsigned v1 = hbp[(e1.x & 0xFFFFF) * 64 + lane];
    unsigned v2 = hbp[(e2.x & 0xFFFFF) * 64 + lane];
    unsigned v3 = hbp[(e3.x & 0xFFFFF) * 64 + lane];
#pragma unroll
    for (int u = 0; u < 4; ++u) {
      int2 e = (u == 0) ? e0 : (u == 1) ? e1 : (u == 2) ? e2 : e3;
      unsigned v = (u == 0) ? v0 : (u == 1) ? v1 : (u == 2) ? v2 : v3;
      union { int i; float f; } nb; nb.i = e.y;
      int r = e.x >> 20;
      union { unsigned u32; float f; } lo, hi;
      lo.u32 = v << 16; hi.u32 = v & 0xFFFF0000u;
#pragma unroll
      for (int rr = 0; rr < RNUM; ++rr)
        if (r == rr) { acc[rr][0] += nb.f * lo.f; acc[rr][1] += nb.f * hi.f; }
    }
  }
  for (; j < len; ++j) {
    int2 e = ep[j];
    union { int i; float f; } nb; nb.i = e.y;
    int r = e.x >> 20;
    unsigned v = hbp[(e.x & 0xFFFFF) * 64 + lane];
    union { unsigned u32; float f; } lo, hi;
    lo.u32 = v << 16; hi.u32 = v & 0xFFFF0000u;
#pragma unroll
    for (int rr = 0; rr < RNUM; ++rr)
      if (r == rr) { acc[rr][0] += nb.f * lo.f; acc[rr][1] += nb.f * hi.f; }
  }
  unsigned* Arow = (unsigned*)(A + (size_t)wave * KA);
#pragma unroll
  for (int rr = 0; rr < RNUM; ++rr)
    Arow[rr * 64 + lane] = (unsigned)f2bf(acc[rr][0])
                         | ((unsigned)f2bf(acc[rr][1]) << 16);
}

// ---- GEMM: [NN x 768] @ [768 x 128], bf16 MFMA 16x16x32, relu fused ---------
// Block = 256 (4 waves), each wave = 16-row strip x 128 cols (8 n-tiles).
// k-chunks 0..4 read from A (stride 640); chunk 5 reads hb directly.
// B chunk staged in LDS in FRAG-LINEAR order -> ds_read_b128 at lane*16B,
// conflict-free.
__global__ __launch_bounds__(256, 4) void k_gemm(
    const unsigned short* __restrict__ A, const unsigned short* __restrict__ hb,
    const unsigned short* __restrict__ Bt, float* __restrict__ out) {
  __shared__ __align__(16) unsigned short Bl[4 * 8 * 64 * 8];  // 32 KiB
  int tid = threadIdx.x;
  int wv = tid >> 6, lane = tid & 63;
  int m = lane & 15, q = lane >> 4;
  int row0 = blockIdx.x * 64 + wv * 16;
  float4v acc[8];
#pragma unroll
  for (int i = 0; i < 8; ++i) acc[i] = (float4v){0.f, 0.f, 0.f, 0.f};

  int arow = row0 + m;
  if (arow >= NN) arow = NN - 1;            // clamp; store is guarded
  const unsigned short* Ap = A + (size_t)arow * KA + q * 8;
  const unsigned short* Hp = hb + (size_t)arow * FEAT + q * 8;

  for (int kc = 0; kc < 6; ++kc) {
    // stage B chunk kc (128 k-values x 128 n) into frag-linear LDS
    for (int i = tid; i < 2048; i += 256) {
      int ks = i >> 9, n0 = (i >> 6) & 7, ln = i & 63;
      int bn = n0 * 16 + (ln & 15);
      int bk = kc * 128 + ks * 32 + ((ln >> 4) << 3);
      *(short8*)&Bl[i * 8] = *(const short8*)&Bt[bn * KTOT + bk];
    }
    __syncthreads();
    const unsigned short* abase = (kc < 5) ? (Ap + kc * 128) : Hp;
#pragma unroll
    for (int ks = 0; ks < 4; ++ks) {
      short8 af = *(const short8*)(abase + ks * 32);
#pragma unroll
      for (int n0 = 0; n0 < 8; ++n0) {
        short8 bf = *(const short8*)&Bl[((ks * 8 + n0) * 64 + lane) * 8];
        acc[n0] = __builtin_amdgcn_mfma_f32_16x16x32_bf16(af, bf, acc[n0], 0, 0, 0);
      }
    }
    __syncthreads();
  }
  // epilogue: C/D layout col=lane&15, row=q*4+reg  [m89-verified]
#pragma unroll
  for (int n0 = 0; n0 < 8; ++n0) {
#pragma unroll
    for (int r = 0; r < 4; ++r) {
      int row = row0 + q * 4 + r;
      if (row < NN) {
        float v = acc[n0][r];
        out[(size_t)row * FEAT + n0 * 16 + m] = v > 0.f ? v : 0.f;
      }
    }
  }
}

// ---- slow-but-correct fallback if ws_size is too small ----------------------
__global__ void k_slow_mm(const float* __restrict__ h, const float* __restrict__ W0,
                          float* __restrict__ out) {
  __shared__ float hn[128];
  int n = blockIdx.x, t = threadIdx.x;
  hn[t] = h[(size_t)n * 128 + t];
  __syncthreads();
  float a = 0.f;
  for (int i = 0; i < 128; ++i) a += hn[i] * W0[i * 128 + t];
  out[(size_t)n * 128 + t] = a;
}
__global__ void k_slow_edge(const float* __restrict__ h, const float* __restrict__ weight,
                            const float* __restrict__ norm, const int* __restrict__ src,
                            const int* __restrict__ dst, const int* __restrict__ eid,
                            float* __restrict__ out) {
  __shared__ float hs[128];
  int e = blockIdx.x, t = threadIdx.x;
  hs[t] = h[(size_t)src[e] * 128 + t];
  __syncthreads();
  const float* W = weight + (size_t)eid[e] * 16384;
  float a = 0.f;
  for (int i = 0; i < 128; ++i) a += hs[i] * W[i * 128 + t];
  atomicAdd(&out[(size_t)dst[e] * 128 + t], a * norm[e]);
}
__global__ void k_slow_relu(float* out) {
  int i = blockIdx.x * 256 + threadIdx.x;
  if (i < NN * FEAT) out[i] = fmaxf(out[i], 0.f);
}

extern "C" void kernel_launch(void* const* d_in, const int* in_sizes, int n_in,
                              void* d_out, int out_size, void* d_ws, size_t ws_size,
                              hipStream_t stream) {
  const float* h      = (const float*)d_in[0];
  const float* weight = (const float*)d_in[1];
  const float* W0     = (const float*)d_in[2];
  const float* norm   = (const float*)d_in[3];
  const int*   src    = (const int*)d_in[4];
  const int*   dst    = (const int*)d_in[5];
  const int*   eid    = (const int*)d_in[6];
  float* out = (float*)d_out;

  char* ws = (char*)d_ws;
  size_t off = 0;
  auto wsalloc = [&](size_t bytes) -> char* {
    char* p = ws + off;
    off += (bytes + 255) & ~(size_t)255;
    return p;
  };
  unsigned short* A   = (unsigned short*)wsalloc((size_t)NN * KA * 2);    // 128 MB
  unsigned short* hb  = (unsigned short*)wsalloc((size_t)NN * FEAT * 2);  // 25.6 MB
  unsigned short* Bt  = (unsigned short*)wsalloc((size_t)FEAT * KTOT * 2);
  int*   deg      = (int*)wsalloc((size_t)NN * 4);
  int*   offs     = (int*)wsalloc((size_t)NN * 4);
  int*   cursor   = (int*)wsalloc((size_t)NN * 4);
  int*   total    = (int*)wsalloc(256);
  int2*  s_edge   = (int2*)wsalloc((size_t)NE * 8);

  if (ws_size >= off) {
    hipMemsetAsync(deg, 0, (size_t)NN * 4, stream);
    k_setup  <<<HIST_B + PREP_B, 256, 0, stream>>>(dst, h, weight, W0, deg, hb, Bt,
                                                   total);
    k_alloc  <<<(NN + 255) / 256, 256, 0, stream>>>(deg, offs, cursor, total);
    k_scatter<<<(NE + 255) / 256, 256, 0, stream>>>(src, dst, eid, norm, cursor,
                                                    s_edge);
    k_agg    <<<(NN + 3) / 4, 256, 0, stream>>>(hb, offs, deg, s_edge, A);
    k_gemm   <<<(NN + 63) / 64, 256, 0, stream>>>(A, hb, Bt, out);
  } else {
    // workspace too small for the fast path: correct fallback
    k_slow_mm  <<<NN, 128, 0, stream>>>(h, W0, out);
    k_slow_edge<<<NE, 128, 0, stream>>>(h, weight, norm, src, dst, eid, out);
    k_slow_relu<<<(NN * FEAT + 255) / 256, 256, 0, stream>>>(out);
  }
}

// Round 4
// 297.525 us; speedup vs baseline: 1.2420x; 1.0525x over previous
//
#include <hip/hip_runtime.h>
#include <hip/hip_bf16.h>

// RGCN layer: out = relu(h@W0 + segment_sum(norm * h[src] @ W[rel], dst))
// Strategy: per-(node,relation) aggregation in IN space (640-wide bf16 A),
// then ONE [N, 768] @ [768, 128] bf16 MFMA GEMM where the last 128-wide
// k-chunk of A is read directly from hb (bf16 h).
// R4: k_gemm M-tile 64->128 rows/block (wave = 2 strips, acc[2][8]) to
// amortize the 192KB/block B staging over 2x MFMA (was MfmaUtil 10%,
// latency-bound at 31% occupancy).

#define NN   100000
#define NE   600000
#define FEAT 128
#define RNUM 5
#define KTOT 768   // GEMM K: 5*128 (relations) + 128 (identity/W0 part)
#define KA   640   // materialized A width (relations only)

#define HIST_B 2344            // ceil(NE/256)
#define PREP_T (NN * 32 + FEAT * KTOT)
#define PREP_B ((PREP_T + 255) / 256)

typedef __attribute__((ext_vector_type(8))) short short8;
typedef __attribute__((ext_vector_type(4))) float float4v;

static __device__ __forceinline__ unsigned short f2bf(float x) {
  union { float f; unsigned u; } v; v.f = x;
  unsigned r = v.u + 0x7FFFu + ((v.u >> 16) & 1u);  // RNE
  return (unsigned short)(r >> 16);
}

// ---- merged: dst histogram + (h -> bf16 hb, stacked/transposed bf16 Bt) -----
__global__ void k_setup(const int* __restrict__ dst, const float* __restrict__ h,
                        const float* __restrict__ weight, const float* __restrict__ W0,
                        int* __restrict__ deg, unsigned short* __restrict__ hb,
                        unsigned short* __restrict__ Bt, int* __restrict__ total) {
  int bid = blockIdx.x;
  if (bid == 0 && threadIdx.x == 0) *total = 0;
  if (bid < HIST_B) {
    int e = bid * 256 + threadIdx.x;
    if (e < NE) atomicAdd(&deg[dst[e]], 1);
  } else {
    int t = (bid - HIST_B) * 256 + threadIdx.x;
    if (t < NN * 32) {                     // 4 h-elements per thread
      float4v v = *(const float4v*)(h + (size_t)t * 4);
      unsigned long long p = (unsigned long long)f2bf(v[0])
                           | ((unsigned long long)f2bf(v[1]) << 16)
                           | ((unsigned long long)f2bf(v[2]) << 32)
                           | ((unsigned long long)f2bf(v[3]) << 48);
      *(unsigned long long*)(hb + (size_t)t * 4) = p;
    } else {
      int u = t - NN * 32;
      if (u < FEAT * KTOT) {
        int o = u / KTOT;
        int k = u - o * KTOT;
        float v = (k < 640) ? weight[(k >> 7) * 16384 + (k & 127) * 128 + o]
                            : W0[(k - 640) * 128 + o];
        Bt[u] = f2bf(v);
      }
    }
  }
}

// Unordered segment allocation: segments need not be sorted, only contiguous
// per node -> no prefix scan, one atomic per node.
__global__ void k_alloc(const int* __restrict__ deg, int* __restrict__ offs,
                        int* __restrict__ cursor, int* __restrict__ total) {
  int n = blockIdx.x * 256 + threadIdx.x;
  if (n < NN) {
    int d = deg[n];
    int s = atomicAdd(total, d);
    offs[n] = s;
    cursor[n] = s;
  }
}

__global__ void k_scatter(const int* __restrict__ src, const int* __restrict__ dst,
                          const int* __restrict__ eid, const float* __restrict__ norm,
                          int* __restrict__ cursor, int2* __restrict__ s_edge) {
  int e = blockIdx.x * 256 + threadIdx.x;
  if (e < NE) {
    int p = atomicAdd(&cursor[dst[e]], 1);
    union { float f; int i; } nb; nb.f = norm[e];
    s_edge[p] = make_int2(src[e] | (eid[e] << 20), nb.i);  // one 8B record
  }
}

// ---- per-node aggregation: one wave per node, lane covers feats (2L, 2L+1) --
// 4-deep manual pipeline: 4 independent edge-record loads, then 4 independent
// 256B gathers in flight, then the fmacs.
__global__ void k_agg(const unsigned short* __restrict__ hb, const int* __restrict__ offs,
                      const int* __restrict__ deg, const int2* __restrict__ s_edge,
                      unsigned short* __restrict__ A) {
  int wave = (blockIdx.x * 256 + threadIdx.x) >> 6;
  int lane = threadIdx.x & 63;
  if (wave >= NN) return;
  int start = offs[wave], len = deg[wave];
  float acc[RNUM][2] = {};
  const unsigned* hbp = (const unsigned*)hb;
  const int2* ep = s_edge + start;

  int j = 0;
  for (; j + 4 <= len; j += 4) {
    int2 e0 = ep[j], e1 = ep[j + 1], e2 = ep[j + 2], e3 = ep[j + 3];
    unsigned v0 = hbp[(e0.x & 0xFFFFF) * 64 + lane];
    unsigned v1 = hbp[(e1.x & 0xFFFFF) * 64 + lane];
    unsigned v2 = hbp[(e2.x & 0xFFFFF) * 64 + lane];
    unsigned v3 = hbp[(e3.x & 0xFFFFF) * 64 + lane];
#pragma unroll
    for (int u = 0; u < 4; ++u) {
      int2 e = (u == 0) ? e0 : (u == 1) ? e1 : (u == 2) ? e2 : e3;
      unsigned v = (u == 0) ? v0 : (u == 1) ? v1 : (u == 2) ? v2 : v3;
      union { int i; float f; } nb; nb.i = e.y;
      int r = e.x >> 20;
      union { unsigned u32; float f; } lo, hi;
      lo.u32 = v << 16; hi.u32 = v & 0xFFFF0000u;
#pragma unroll
      for (int rr = 0; rr < RNUM; ++rr)
        if (r == rr) { acc[rr][0] += nb.f * lo.f; acc[rr][1] += nb.f * hi.f; }
    }
  }
  for (; j < len; ++j) {
    int2 e = ep[j];
    union { int i; float f; } nb; nb.i = e.y;
    int r = e.x >> 20;
    unsigned v = hbp[(e.x & 0xFFFFF) * 64 + lane];
    union { unsigned u32; float f; } lo, hi;
    lo.u32 = v << 16; hi.u32 = v & 0xFFFF0000u;
#pragma unroll
    for (int rr = 0; rr < RNUM; ++rr)
      if (r == rr) { acc[rr][0] += nb.f * lo.f; acc[rr][1] += nb.f * hi.f; }
  }
  unsigned* Arow = (unsigned*)(A + (size_t)wave * KA);
#pragma unroll
  for (int rr = 0; rr < RNUM; ++rr)
    Arow[rr * 64 + lane] = (unsigned)f2bf(acc[rr][0])
                         | ((unsigned)f2bf(acc[rr][1]) << 16);
}

// ---- GEMM: [NN x 768] @ [768 x 128], bf16 MFMA 16x16x32, relu fused ---------
// Block = 256 (4 waves), M-tile = 128 rows: each wave owns 2 strips of 16 rows
// x 128 cols (8 n-tiles). k-chunks 0..4 read A (stride 640); chunk 5 reads hb.
// B chunk staged in LDS in FRAG-LINEAR order -> ds_read_b128 at lane*16B,
// conflict-free; 32KB LDS -> up to 3 blocks/CU at launch_bounds(256,3).
__global__ __launch_bounds__(256, 3) void k_gemm(
    const unsigned short* __restrict__ A, const unsigned short* __restrict__ hb,
    const unsigned short* __restrict__ Bt, float* __restrict__ out) {
  __shared__ __align__(16) unsigned short Bl[4 * 8 * 64 * 8];  // 32 KiB
  int tid = threadIdx.x;
  int wv = tid >> 6, lane = tid & 63;
  int m = lane & 15, q = lane >> 4;
  int row0 = blockIdx.x * 128 + wv * 32;   // this wave: rows row0..row0+31
  float4v acc[2][8];
#pragma unroll
  for (int s = 0; s < 2; ++s)
#pragma unroll
    for (int i = 0; i < 8; ++i) acc[s][i] = (float4v){0.f, 0.f, 0.f, 0.f};

  int ar0 = row0 + m;       if (ar0 >= NN) ar0 = NN - 1;   // clamp; store guarded
  int ar1 = row0 + 16 + m;  if (ar1 >= NN) ar1 = NN - 1;
  const unsigned short* Ap0 = A + (size_t)ar0 * KA + q * 8;
  const unsigned short* Ap1 = A + (size_t)ar1 * KA + q * 8;
  const unsigned short* Hp0 = hb + (size_t)ar0 * FEAT + q * 8;
  const unsigned short* Hp1 = hb + (size_t)ar1 * FEAT + q * 8;

  for (int kc = 0; kc < 6; ++kc) {
    // stage B chunk kc (128 k-values x 128 n) into frag-linear LDS
    for (int i = tid; i < 2048; i += 256) {
      int ks = i >> 9, n0 = (i >> 6) & 7, ln = i & 63;
      int bn = n0 * 16 + (ln & 15);
      int bk = kc * 128 + ks * 32 + ((ln >> 4) << 3);
      *(short8*)&Bl[i * 8] = *(const short8*)&Bt[bn * KTOT + bk];
    }
    __syncthreads();
    const unsigned short* a0 = (kc < 5) ? (Ap0 + kc * 128) : Hp0;
    const unsigned short* a1 = (kc < 5) ? (Ap1 + kc * 128) : Hp1;
#pragma unroll
    for (int ks = 0; ks < 4; ++ks) {
      short8 af0 = *(const short8*)(a0 + ks * 32);
      short8 af1 = *(const short8*)(a1 + ks * 32);
#pragma unroll
      for (int n0 = 0; n0 < 8; ++n0) {
        short8 bf = *(const short8*)&Bl[((ks * 8 + n0) * 64 + lane) * 8];
        acc[0][n0] = __builtin_amdgcn_mfma_f32_16x16x32_bf16(af0, bf, acc[0][n0], 0, 0, 0);
        acc[1][n0] = __builtin_amdgcn_mfma_f32_16x16x32_bf16(af1, bf, acc[1][n0], 0, 0, 0);
      }
    }
    __syncthreads();
  }
  // epilogue: C/D layout col=lane&15, row=q*4+reg  [m89-verified]
#pragma unroll
  for (int s = 0; s < 2; ++s) {
#pragma unroll
    for (int n0 = 0; n0 < 8; ++n0) {
#pragma unroll
      for (int r = 0; r < 4; ++r) {
        int row = row0 + s * 16 + q * 4 + r;
        if (row < NN) {
          float v = acc[s][n0][r];
          out[(size_t)row * FEAT + n0 * 16 + m] = v > 0.f ? v : 0.f;
        }
      }
    }
  }
}

// ---- slow-but-correct fallback if ws_size is too small ----------------------
__global__ void k_slow_mm(const float* __restrict__ h, const float* __restrict__ W0,
                          float* __restrict__ out) {
  __shared__ float hn[128];
  int n = blockIdx.x, t = threadIdx.x;
  hn[t] = h[(size_t)n * 128 + t];
  __syncthreads();
  float a = 0.f;
  for (int i = 0; i < 128; ++i) a += hn[i] * W0[i * 128 + t];
  out[(size_t)n * 128 + t] = a;
}
__global__ void k_slow_edge(const float* __restrict__ h, const float* __restrict__ weight,
                            const float* __restrict__ norm, const int* __restrict__ src,
                            const int* __restrict__ dst, const int* __restrict__ eid,
                            float* __restrict__ out) {
  __shared__ float hs[128];
  int e = blockIdx.x, t = threadIdx.x;
  hs[t] = h[(size_t)src[e] * 128 + t];
  __syncthreads();
  const float* W = weight + (size_t)eid[e] * 16384;
  float a = 0.f;
  for (int i = 0; i < 128; ++i) a += hs[i] * W[i * 128 + t];
  atomicAdd(&out[(size_t)dst[e] * 128 + t], a * norm[e]);
}
__global__ void k_slow_relu(float* out) {
  int i = blockIdx.x * 256 + threadIdx.x;
  if (i < NN * FEAT) out[i] = fmaxf(out[i], 0.f);
}

extern "C" void kernel_launch(void* const* d_in, const int* in_sizes, int n_in,
                              void* d_out, int out_size, void* d_ws, size_t ws_size,
                              hipStream_t stream) {
  const float* h      = (const float*)d_in[0];
  const float* weight = (const float*)d_in[1];
  const float* W0     = (const float*)d_in[2];
  const float* norm   = (const float*)d_in[3];
  const int*   src    = (const int*)d_in[4];
  const int*   dst    = (const int*)d_in[5];
  const int*   eid    = (const int*)d_in[6];
  float* out = (float*)d_out;

  char* ws = (char*)d_ws;
  size_t off = 0;
  auto wsalloc = [&](size_t bytes) -> char* {
    char* p = ws + off;
    off += (bytes + 255) & ~(size_t)255;
    return p;
  };
  unsigned short* A   = (unsigned short*)wsalloc((size_t)NN * KA * 2);    // 128 MB
  unsigned short* hb  = (unsigned short*)wsalloc((size_t)NN * FEAT * 2);  // 25.6 MB
  unsigned short* Bt  = (unsigned short*)wsalloc((size_t)FEAT * KTOT * 2);
  int*   deg      = (int*)wsalloc((size_t)NN * 4);
  int*   offs     = (int*)wsalloc((size_t)NN * 4);
  int*   cursor   = (int*)wsalloc((size_t)NN * 4);
  int*   total    = (int*)wsalloc(256);
  int2*  s_edge   = (int2*)wsalloc((size_t)NE * 8);

  if (ws_size >= off) {
    hipMemsetAsync(deg, 0, (size_t)NN * 4, stream);
    k_setup  <<<HIST_B + PREP_B, 256, 0, stream>>>(dst, h, weight, W0, deg, hb, Bt,
                                                   total);
    k_alloc  <<<(NN + 255) / 256, 256, 0, stream>>>(deg, offs, cursor, total);
    k_scatter<<<(NE + 255) / 256, 256, 0, stream>>>(src, dst, eid, norm, cursor,
                                                    s_edge);
    k_agg    <<<(NN + 3) / 4, 256, 0, stream>>>(hb, offs, deg, s_edge, A);
    k_gemm   <<<(NN + 127) / 128, 256, 0, stream>>>(A, hb, Bt, out);
  } else {
    // workspace too small for the fast path: correct fallback
    k_slow_mm  <<<NN, 128, 0, stream>>>(h, W0, out);
    k_slow_edge<<<NE, 128, 0, stream>>>(h, weight, norm, src, dst, eid, out);
    k_slow_relu<<<(NN * FEAT + 255) / 256, 256, 0, stream>>>(out);
  }
}

// Round 5
// 281.141 us; speedup vs baseline: 1.3144x; 1.0583x over previous
//
#include <hip/hip_runtime.h>
#include <hip/hip_bf16.h>

// RGCN layer: out = relu(h@W0 + segment_sum(norm * h[src] @ W[rel], dst))
// Strategy: per-(node,relation) aggregation in IN space (640-wide bf16 A),
// then ONE [N, 768] @ [768, 128] bf16 MFMA GEMM (last k-chunk reads hb).
// R5: (a) k_alloc wave-scan (was 100k same-address atomics -> serialized),
//     (b) k_gemm M-tile 256/block, (c) Bt pre-arranged frag-linear +
//     global_load_lds width-16 staging (no VGPR round-trip, no addr math).

#define NN   100000
#define NE   600000
#define FEAT 128
#define RNUM 5
#define KTOT 768   // GEMM K: 5*128 (relations) + 128 (identity/W0 part)
#define KA   640   // materialized A width (relations only)

#define HIST_B 2344            // ceil(NE/256)
#define PREP_T (NN * 32 + FEAT * KTOT)
#define PREP_B ((PREP_T + 255) / 256)

#define AS1 __attribute__((address_space(1)))
#define AS3 __attribute__((address_space(3)))

typedef __attribute__((ext_vector_type(8))) short short8;
typedef __attribute__((ext_vector_type(4))) float float4v;

static __device__ __forceinline__ unsigned short f2bf(float x) {
  union { float f; unsigned u; } v; v.f = x;
  unsigned r = v.u + 0x7FFFu + ((v.u >> 16) & 1u);  // RNE
  return (unsigned short)(r >> 16);
}

// ---- merged: dst histogram + (h -> bf16 hb, frag-linear bf16 Bt) ------------
// Bt layout: 16B granule g = ((kc*4+ks)*8+n0)*64+ln holds B[k][o] for
// o = n0*16+(ln&15), k = kc*128+ks*32+((ln>>4)<<3)+j, j=0..7 — exactly the
// LDS image k_gemm wants, so staging is a contiguous copy.
__global__ void k_setup(const int* __restrict__ dst, const float* __restrict__ h,
                        const float* __restrict__ weight, const float* __restrict__ W0,
                        int* __restrict__ deg, unsigned short* __restrict__ hb,
                        unsigned short* __restrict__ Bt, int* __restrict__ total) {
  int bid = blockIdx.x;
  if (bid == 0 && threadIdx.x == 0) *total = 0;
  if (bid < HIST_B) {
    int e = bid * 256 + threadIdx.x;
    if (e < NE) atomicAdd(&deg[dst[e]], 1);
  } else {
    int t = (bid - HIST_B) * 256 + threadIdx.x;
    if (t < NN * 32) {                     // 4 h-elements per thread
      float4v v = *(const float4v*)(h + (size_t)t * 4);
      unsigned long long p = (unsigned long long)f2bf(v[0])
                           | ((unsigned long long)f2bf(v[1]) << 16)
                           | ((unsigned long long)f2bf(v[2]) << 32)
                           | ((unsigned long long)f2bf(v[3]) << 48);
      *(unsigned long long*)(hb + (size_t)t * 4) = p;
    } else {
      int u = t - NN * 32;
      if (u < FEAT * KTOT) {
        int j = u & 7, g = u >> 3;
        int ln = g & 63, n0 = (g >> 6) & 7, ks = (g >> 9) & 3, kc = g >> 11;
        int o = n0 * 16 + (ln & 15);
        int k = kc * 128 + ks * 32 + ((ln >> 4) << 3) + j;
        float v = (k < 640) ? weight[(k >> 7) * 16384 + (k & 127) * 128 + o]
                            : W0[(k - 640) * 128 + o];
        Bt[u] = f2bf(v);
      }
    }
  }
}

// Unordered segment allocation via intra-wave scan: ONE atomic per wave
// (1563 total) instead of 100k same-address atomics (which serialize at the
// owning L2 bank).
__global__ void k_alloc(const int* __restrict__ deg, int* __restrict__ offs,
                        int* __restrict__ cursor, int* __restrict__ total) {
  int n = blockIdx.x * 256 + threadIdx.x;
  int lane = threadIdx.x & 63;
  int d = (n < NN) ? deg[n] : 0;
  int scan = d;
#pragma unroll
  for (int o = 1; o < 64; o <<= 1) {
    int t = __shfl_up(scan, o, 64);
    if (lane >= o) scan += t;
  }
  int base = 0;
  if (lane == 63) base = atomicAdd(total, scan);   // scan@63 == wave sum
  base = __shfl(base, 63, 64);
  if (n < NN) {
    int s = base + scan - d;
    offs[n] = s;
    cursor[n] = s;
  }
}

__global__ void k_scatter(const int* __restrict__ src, const int* __restrict__ dst,
                          const int* __restrict__ eid, const float* __restrict__ norm,
                          int* __restrict__ cursor, int2* __restrict__ s_edge) {
  int e = blockIdx.x * 256 + threadIdx.x;
  if (e < NE) {
    int p = atomicAdd(&cursor[dst[e]], 1);
    union { float f; int i; } nb; nb.f = norm[e];
    s_edge[p] = make_int2(src[e] | (eid[e] << 20), nb.i);  // one 8B record
  }
}

// ---- per-node aggregation: one wave per node, lane covers feats (2L, 2L+1) --
// 4-deep manual pipeline: 4 independent edge-record loads, then 4 independent
// 256B gathers in flight, then the fmacs.
__global__ void k_agg(const unsigned short* __restrict__ hb, const int* __restrict__ offs,
                      const int* __restrict__ deg, const int2* __restrict__ s_edge,
                      unsigned short* __restrict__ A) {
  int wave = (blockIdx.x * 256 + threadIdx.x) >> 6;
  int lane = threadIdx.x & 63;
  if (wave >= NN) return;
  int start = offs[wave], len = deg[wave];
  float acc[RNUM][2] = {};
  const unsigned* hbp = (const unsigned*)hb;
  const int2* ep = s_edge + start;

  int j = 0;
  for (; j + 4 <= len; j += 4) {
    int2 e0 = ep[j], e1 = ep[j + 1], e2 = ep[j + 2], e3 = ep[j + 3];
    unsigned v0 = hbp[(e0.x & 0xFFFFF) * 64 + lane];
    unsigned v1 = hbp[(e1.x & 0xFFFFF) * 64 + lane];
    unsigned v2 = hbp[(e2.x & 0xFFFFF) * 64 + lane];
    unsigned v3 = hbp[(e3.x & 0xFFFFF) * 64 + lane];
#pragma unroll
    for (int u = 0; u < 4; ++u) {
      int2 e = (u == 0) ? e0 : (u == 1) ? e1 : (u == 2) ? e2 : e3;
      unsigned v = (u == 0) ? v0 : (u == 1) ? v1 : (u == 2) ? v2 : v3;
      union { int i; float f; } nb; nb.i = e.y;
      int r = e.x >> 20;
      union { unsigned u32; float f; } lo, hi;
      lo.u32 = v << 16; hi.u32 = v & 0xFFFF0000u;
#pragma unroll
      for (int rr = 0; rr < RNUM; ++rr)
        if (r == rr) { acc[rr][0] += nb.f * lo.f; acc[rr][1] += nb.f * hi.f; }
    }
  }
  for (; j < len; ++j) {
    int2 e = ep[j];
    union { int i; float f; } nb; nb.i = e.y;
    int r = e.x >> 20;
    unsigned v = hbp[(e.x & 0xFFFFF) * 64 + lane];
    union { unsigned u32; float f; } lo, hi;
    lo.u32 = v << 16; hi.u32 = v & 0xFFFF0000u;
#pragma unroll
    for (int rr = 0; rr < RNUM; ++rr)
      if (r == rr) { acc[rr][0] += nb.f * lo.f; acc[rr][1] += nb.f * hi.f; }
  }
  unsigned* Arow = (unsigned*)(A + (size_t)wave * KA);
#pragma unroll
  for (int rr = 0; rr < RNUM; ++rr)
    Arow[rr * 64 + lane] = (unsigned)f2bf(acc[rr][0])
                         | ((unsigned)f2bf(acc[rr][1]) << 16);
}

// ---- GEMM: [NN x 768] @ [768 x 128], bf16 MFMA 16x16x32, relu fused ---------
// Block = 256 (4 waves), M-tile = 256 rows: each wave owns 4 strips of 16 rows
// x 128 cols. Per chunk: 8 global_load_lds dwordx4 per thread stage 32KB of
// frag-linear Bt straight into LDS; 128 MFMA/wave between barriers.
// k-chunks 0..4 read A (stride 640); chunk 5 reads hb.
__global__ __launch_bounds__(256, 2) void k_gemm(
    const unsigned short* __restrict__ A, const unsigned short* __restrict__ hb,
    const unsigned short* __restrict__ Bt, float* __restrict__ out) {
  __shared__ __align__(16) unsigned short Bl[2048 * 8];  // 32 KiB
  int tid = threadIdx.x;
  int wv = tid >> 6, lane = tid & 63;
  int m = lane & 15, q = lane >> 4;
  int row0 = blockIdx.x * 256 + wv * 64;   // this wave: rows row0..row0+63
  float4v acc[4][8];
#pragma unroll
  for (int s = 0; s < 4; ++s)
#pragma unroll
    for (int i = 0; i < 8; ++i) acc[s][i] = (float4v){0.f, 0.f, 0.f, 0.f};

  const unsigned short* Ap[4];
  const unsigned short* Hp[4];
#pragma unroll
  for (int s = 0; s < 4; ++s) {
    int ar = row0 + s * 16 + m;
    if (ar >= NN) ar = NN - 1;             // clamp; store is guarded
    Ap[s] = A + (size_t)ar * KA + q * 8;
    Hp[s] = hb + (size_t)ar * FEAT + q * 8;
  }

  for (int kc = 0; kc < 6; ++kc) {
    // stage B chunk kc (32 KB, already frag-linear) via async global->LDS
#pragma unroll
    for (int it = 0; it < 8; ++it) {
      int idx = it * 256 + tid;            // 0..2047, lane-contiguous per wave
      __builtin_amdgcn_global_load_lds(
          (const AS1 void*)(Bt + (size_t)kc * 16384 + idx * 8),
          (AS3 void*)(Bl + idx * 8), 16, 0, 0);
    }
    __syncthreads();                       // drains vmcnt -> LDS image complete
#pragma unroll
    for (int ks = 0; ks < 4; ++ks) {
      short8 af[4];
#pragma unroll
      for (int s = 0; s < 4; ++s)
        af[s] = *(const short8*)((kc < 5 ? Ap[s] + kc * 128 : Hp[s]) + ks * 32);
#pragma unroll
      for (int n0 = 0; n0 < 8; ++n0) {
        short8 bf = *(const short8*)&Bl[((ks * 8 + n0) * 64 + lane) * 8];
#pragma unroll
        for (int s = 0; s < 4; ++s)
          acc[s][n0] = __builtin_amdgcn_mfma_f32_16x16x32_bf16(af[s], bf, acc[s][n0], 0, 0, 0);
      }
    }
    __syncthreads();
  }
  // epilogue: C/D layout col=lane&15, row=q*4+reg  [m89-verified]
#pragma unroll
  for (int s = 0; s < 4; ++s) {
#pragma unroll
    for (int n0 = 0; n0 < 8; ++n0) {
#pragma unroll
      for (int r = 0; r < 4; ++r) {
        int row = row0 + s * 16 + q * 4 + r;
        if (row < NN) {
          float v = acc[s][n0][r];
          out[(size_t)row * FEAT + n0 * 16 + m] = v > 0.f ? v : 0.f;
        }
      }
    }
  }
}

// ---- slow-but-correct fallback if ws_size is too small ----------------------
__global__ void k_slow_mm(const float* __restrict__ h, const float* __restrict__ W0,
                          float* __restrict__ out) {
  __shared__ float hn[128];
  int n = blockIdx.x, t = threadIdx.x;
  hn[t] = h[(size_t)n * 128 + t];
  __syncthreads();
  float a = 0.f;
  for (int i = 0; i < 128; ++i) a += hn[i] * W0[i * 128 + t];
  out[(size_t)n * 128 + t] = a;
}
__global__ void k_slow_edge(const float* __restrict__ h, const float* __restrict__ weight,
                            const float* __restrict__ norm, const int* __restrict__ src,
                            const int* __restrict__ dst, const int* __restrict__ eid,
                            float* __restrict__ out) {
  __shared__ float hs[128];
  int e = blockIdx.x, t = threadIdx.x;
  hs[t] = h[(size_t)src[e] * 128 + t];
  __syncthreads();
  const float* W = weight + (size_t)eid[e] * 16384;
  float a = 0.f;
  for (int i = 0; i < 128; ++i) a += hs[i] * W[i * 128 + t];
  atomicAdd(&out[(size_t)dst[e] * 128 + t], a * norm[e]);
}
__global__ void k_slow_relu(float* out) {
  int i = blockIdx.x * 256 + threadIdx.x;
  if (i < NN * FEAT) out[i] = fmaxf(out[i], 0.f);
}

extern "C" void kernel_launch(void* const* d_in, const int* in_sizes, int n_in,
                              void* d_out, int out_size, void* d_ws, size_t ws_size,
                              hipStream_t stream) {
  const float* h      = (const float*)d_in[0];
  const float* weight = (const float*)d_in[1];
  const float* W0     = (const float*)d_in[2];
  const float* norm   = (const float*)d_in[3];
  const int*   src    = (const int*)d_in[4];
  const int*   dst    = (const int*)d_in[5];
  const int*   eid    = (const int*)d_in[6];
  float* out = (float*)d_out;

  char* ws = (char*)d_ws;
  size_t off = 0;
  auto wsalloc = [&](size_t bytes) -> char* {
    char* p = ws + off;
    off += (bytes + 255) & ~(size_t)255;
    return p;
  };
  unsigned short* A   = (unsigned short*)wsalloc((size_t)NN * KA * 2);    // 128 MB
  unsigned short* hb  = (unsigned short*)wsalloc((size_t)NN * FEAT * 2);  // 25.6 MB
  unsigned short* Bt  = (unsigned short*)wsalloc((size_t)FEAT * KTOT * 2);
  int*   deg      = (int*)wsalloc((size_t)NN * 4);
  int*   offs     = (int*)wsalloc((size_t)NN * 4);
  int*   cursor   = (int*)wsalloc((size_t)NN * 4);
  int*   total    = (int*)wsalloc(256);
  int2*  s_edge   = (int2*)wsalloc((size_t)NE * 8);

  if (ws_size >= off) {
    hipMemsetAsync(deg, 0, (size_t)NN * 4, stream);
    k_setup  <<<HIST_B + PREP_B, 256, 0, stream>>>(dst, h, weight, W0, deg, hb, Bt,
                                                   total);
    k_alloc  <<<(NN + 255) / 256, 256, 0, stream>>>(deg, offs, cursor, total);
    k_scatter<<<(NE + 255) / 256, 256, 0, stream>>>(src, dst, eid, norm, cursor,
                                                    s_edge);
    k_agg    <<<(NN + 3) / 4, 256, 0, stream>>>(hb, offs, deg, s_edge, A);
    k_gemm   <<<(NN + 255) / 256, 256, 0, stream>>>(A, hb, Bt, out);
  } else {
    // workspace too small for the fast path: correct fallback
    k_slow_mm  <<<NN, 128, 0, stream>>>(h, W0, out);
    k_slow_edge<<<NE, 128, 0, stream>>>(h, weight, norm, src, dst, eid, out);
    k_slow_relu<<<(NN * FEAT + 255) / 256, 256, 0, stream>>>(out);
  }
}